// Round 1
// baseline (729.897 us; speedup 1.0000x reference)
//
#include <hip/hip_runtime.h>

// DopamineArea: out_spikes = (spikes >= 0.5); S = mean(out_spikes); delta = S - P.
// Output layout: d_out[0..N) = delta, d_out[N..2N) = out_spikes.
// Memory-bound: 512 MiB mandatory traffic -> ~85 us floor at 6.3 TB/s.

#define THRESH 0.5f
#define BLOCK 256

// Kernel 1: read spikes (float4), write out_spikes, accumulate integer spike count.
__global__ __launch_bounds__(BLOCK) void spike_count_kernel(
    const float4* __restrict__ spikes4,
    float4* __restrict__ out_spikes4,
    unsigned int* __restrict__ count,
    int n4)
{
    int i = blockIdx.x * BLOCK + threadIdx.x;
    int local = 0;
    if (i < n4) {
        float4 s = spikes4[i];
        float4 o;
        o.x = (s.x >= THRESH) ? 1.0f : 0.0f;
        o.y = (s.y >= THRESH) ? 1.0f : 0.0f;
        o.z = (s.z >= THRESH) ? 1.0f : 0.0f;
        o.w = (s.w >= THRESH) ? 1.0f : 0.0f;
        out_spikes4[i] = o;
        local = (int)o.x + (int)o.y + (int)o.z + (int)o.w;
    }

    // Wave-64 shuffle reduction.
    #pragma unroll
    for (int off = 32; off > 0; off >>= 1)
        local += __shfl_down(local, off, 64);

    __shared__ int wave_sums[BLOCK / 64];
    int lane = threadIdx.x & 63;
    int wid  = threadIdx.x >> 6;
    if (lane == 0) wave_sums[wid] = local;
    __syncthreads();

    if (threadIdx.x == 0) {
        int total = 0;
        #pragma unroll
        for (int w = 0; w < BLOCK / 64; ++w) total += wave_sums[w];
        atomicAdd(count, (unsigned int)total);  // device-scope by default
    }
}

// Kernel 2: S = count * inv_n; delta = S - P (float4).
__global__ __launch_bounds__(BLOCK) void delta_kernel(
    const float4* __restrict__ P4,
    float4* __restrict__ delta4,
    const unsigned int* __restrict__ count,
    int n4, float inv_n)
{
    __shared__ float S_sh;
    if (threadIdx.x == 0) S_sh = (float)(*count) * inv_n;
    __syncthreads();
    float S = S_sh;

    int i = blockIdx.x * BLOCK + threadIdx.x;
    if (i < n4) {
        float4 p = P4[i];
        float4 d;
        d.x = S - p.x;
        d.y = S - p.y;
        d.z = S - p.z;
        d.w = S - p.w;
        delta4[i] = d;
    }
}

extern "C" void kernel_launch(void* const* d_in, const int* in_sizes, int n_in,
                              void* d_out, int out_size, void* d_ws, size_t ws_size,
                              hipStream_t stream) {
    const float* spikes = (const float*)d_in[0];
    const float* P      = (const float*)d_in[1];
    float* out          = (float*)d_out;

    const int n  = in_sizes[0];          // 33554432, divisible by 4
    const int n4 = n / 4;
    float* delta_out  = out;             // first N floats
    float* spikes_out = out + n;         // second N floats

    unsigned int* count = (unsigned int*)d_ws;

    // d_ws is poisoned 0xAA before every launch; zero the counter (capture-safe).
    hipMemsetAsync(count, 0, sizeof(unsigned int), stream);

    const int grid = (n4 + BLOCK - 1) / BLOCK;  // 32768 blocks

    spike_count_kernel<<<grid, BLOCK, 0, stream>>>(
        (const float4*)spikes, (float4*)spikes_out, count, n4);

    delta_kernel<<<grid, BLOCK, 0, stream>>>(
        (const float4*)P, (float4*)delta_out, count, n4, 1.0f / (float)n);
}

// Round 3
// 451.262 us; speedup vs baseline: 1.6175x; 1.6175x over previous
//
#include <hip/hip_runtime.h>

// DopamineArea: out_spikes = (spikes >= 0.5); S = mean(out_spikes); delta = S - P.
// Output layout: d_out[0..N) = delta, d_out[N..2N) = out_spikes.
// Memory-bound: 512 MiB mandatory HBM traffic -> ~85 us floor at 6.3 TB/s.
//
// R1 lesson: one-element-per-thread with 32768 tiny blocks ran at 532 GB/s
// (block dispatch/teardown-bound, ~28 cy/block). Grid-stride with 2048
// long-lived blocks (8/CU), 16 float4/thread, x4 manual unroll for MLP.
// R2 fix: __builtin_nontemporal_store requires a clang ext_vector type,
// not HIP's float4 class -> use v4f.

#define THRESH 0.5f
#define BLOCK  256
#define GRID   2048   // 8 blocks/CU x 256 CUs co-resident

typedef float v4f __attribute__((ext_vector_type(4)));

__device__ __forceinline__ int spike4(const v4f s, v4f& o) {
    o.x = (s.x >= THRESH) ? 1.0f : 0.0f;
    o.y = (s.y >= THRESH) ? 1.0f : 0.0f;
    o.z = (s.z >= THRESH) ? 1.0f : 0.0f;
    o.w = (s.w >= THRESH) ? 1.0f : 0.0f;
    return (int)o.x + (int)o.y + (int)o.z + (int)o.w;
}

// Kernel 1: stream spikes -> out_spikes, one integer partial count per block.
__global__ __launch_bounds__(BLOCK) void spike_count_kernel(
    const v4f* __restrict__ spikes4,
    v4f* __restrict__ out_spikes4,
    unsigned int* __restrict__ partials,
    int n4)
{
    const int tid    = threadIdx.x;
    const int stride = gridDim.x * BLOCK;
    int i = blockIdx.x * BLOCK + tid;
    int cnt = 0;

    // Main: 4 independent loads in flight per iteration.
    for (; i + 3 * stride < n4; i += 4 * stride) {
        v4f a = spikes4[i];
        v4f b = spikes4[i +     stride];
        v4f c = spikes4[i + 2 * stride];
        v4f d = spikes4[i + 3 * stride];
        v4f oa, ob, oc, od;
        cnt += spike4(a, oa);
        cnt += spike4(b, ob);
        cnt += spike4(c, oc);
        cnt += spike4(d, od);
        __builtin_nontemporal_store(oa, &out_spikes4[i]);
        __builtin_nontemporal_store(ob, &out_spikes4[i +     stride]);
        __builtin_nontemporal_store(oc, &out_spikes4[i + 2 * stride]);
        __builtin_nontemporal_store(od, &out_spikes4[i + 3 * stride]);
    }
    for (; i < n4; i += stride) {
        v4f s = spikes4[i];
        v4f o;
        cnt += spike4(s, o);
        __builtin_nontemporal_store(o, &out_spikes4[i]);
    }

    // Block reduction: wave-64 shuffle -> LDS -> thread 0 stores partial.
    #pragma unroll
    for (int off = 32; off > 0; off >>= 1)
        cnt += __shfl_down(cnt, off, 64);

    __shared__ int wave_sums[BLOCK / 64];
    const int lane = tid & 63;
    const int wid  = tid >> 6;
    if (lane == 0) wave_sums[wid] = cnt;
    __syncthreads();
    if (tid == 0) {
        int total = 0;
        #pragma unroll
        for (int w = 0; w < BLOCK / 64; ++w) total += wave_sums[w];
        partials[blockIdx.x] = (unsigned int)total;
    }
}

// Kernel 2: each block redundantly reduces the partials (8 KB, L2-hot),
// then streams delta = S - P.
__global__ __launch_bounds__(BLOCK) void delta_kernel(
    const v4f* __restrict__ P4,
    v4f* __restrict__ delta4,
    const unsigned int* __restrict__ partials,
    int n_part, int n4, float inv_n)
{
    const int tid = threadIdx.x;

    int c = 0;
    for (int j = tid; j < n_part; j += BLOCK)
        c += (int)partials[j];
    #pragma unroll
    for (int off = 32; off > 0; off >>= 1)
        c += __shfl_down(c, off, 64);

    __shared__ int wave_sums[BLOCK / 64];
    const int lane = tid & 63;
    const int wid  = tid >> 6;
    if (lane == 0) wave_sums[wid] = c;
    __syncthreads();
    int total = 0;
    #pragma unroll
    for (int w = 0; w < BLOCK / 64; ++w) total += wave_sums[w];
    const float S = (float)total * inv_n;   // exact: total <= 2^25, inv_n = 2^-25

    const int stride = gridDim.x * BLOCK;
    int i = blockIdx.x * BLOCK + tid;
    for (; i + 3 * stride < n4; i += 4 * stride) {
        v4f a = P4[i];
        v4f b = P4[i +     stride];
        v4f c4 = P4[i + 2 * stride];
        v4f d = P4[i + 3 * stride];
        v4f oa = S - a;
        v4f ob = S - b;
        v4f oc = S - c4;
        v4f od = S - d;
        __builtin_nontemporal_store(oa, &delta4[i]);
        __builtin_nontemporal_store(ob, &delta4[i +     stride]);
        __builtin_nontemporal_store(oc, &delta4[i + 2 * stride]);
        __builtin_nontemporal_store(od, &delta4[i + 3 * stride]);
    }
    for (; i < n4; i += stride) {
        v4f p = P4[i];
        v4f o = S - p;
        __builtin_nontemporal_store(o, &delta4[i]);
    }
}

extern "C" void kernel_launch(void* const* d_in, const int* in_sizes, int n_in,
                              void* d_out, int out_size, void* d_ws, size_t ws_size,
                              hipStream_t stream) {
    const float* spikes = (const float*)d_in[0];
    const float* P      = (const float*)d_in[1];
    float* out          = (float*)d_out;

    const int n  = in_sizes[0];          // 33554432, divisible by 4
    const int n4 = n / 4;
    float* delta_out  = out;             // first N floats
    float* spikes_out = out + n;         // second N floats

    unsigned int* partials = (unsigned int*)d_ws;  // GRID u32 slots, fully
                                                   // rewritten each call (no memset)

    spike_count_kernel<<<GRID, BLOCK, 0, stream>>>(
        (const v4f*)spikes, (v4f*)spikes_out, partials, n4);

    delta_kernel<<<GRID, BLOCK, 0, stream>>>(
        (const v4f*)P, (v4f*)delta_out, partials, GRID, n4,
        1.0f / (float)n);
}

// Round 4
// 432.906 us; speedup vs baseline: 1.6860x; 1.0424x over previous
//
#include <hip/hip_runtime.h>

// DopamineArea: out_spikes = (spikes >= 0.5); S = mean(out_spikes); delta = S - P.
// Output layout: d_out[0..N) = delta, d_out[N..2N) = out_spikes.
// Memory-bound: 512 MiB mandatory HBM traffic -> ~85 us floor at 6.3 TB/s.
//
// R1 lesson: one-elem-per-thread 32768-block version ran 532 GB/s (cause
//   misdiagnosed as dispatch overhead; arithmetic says dispatch is ~17 us).
// R3 lesson: grid-stride + __builtin_nontemporal_store ran ~1.6 TB/s while
//   the harness's plain fills hit 6.5 TB/s in the same run -> NT store
//   (cache-bypass `nt` flag) is the prime suspect. Dropped here; also moved
//   to contiguous 64 KiB per-block chunks (fill-like sequential addresses).

#define THRESH 0.5f
#define BLOCK  256
#define GRID   2048   // 8 blocks/CU x 256 CUs

typedef float v4f __attribute__((ext_vector_type(4)));

__device__ __forceinline__ int spike4(const v4f s, v4f& o) {
    o.x = (s.x >= THRESH) ? 1.0f : 0.0f;
    o.y = (s.y >= THRESH) ? 1.0f : 0.0f;
    o.z = (s.z >= THRESH) ? 1.0f : 0.0f;
    o.w = (s.w >= THRESH) ? 1.0f : 0.0f;
    return (int)o.x + (int)o.y + (int)o.z + (int)o.w;
}

// Kernel 1: stream spikes -> out_spikes, one integer partial per block.
__global__ __launch_bounds__(BLOCK) void spike_count_kernel(
    const v4f* __restrict__ spikes4,
    v4f* __restrict__ out_spikes4,
    unsigned int* __restrict__ partials,
    int n4, int chunk)
{
    const int tid   = threadIdx.x;
    const int start = blockIdx.x * chunk;
    const int end   = min(start + chunk, n4);
    int cnt = 0;

    int i = start + tid;
    // Main: 4 independent loads in flight, contiguous 4 KiB per wave-group.
    for (; i + 3 * BLOCK < end; i += 4 * BLOCK) {
        v4f a = spikes4[i];
        v4f b = spikes4[i +     BLOCK];
        v4f c = spikes4[i + 2 * BLOCK];
        v4f d = spikes4[i + 3 * BLOCK];
        v4f oa, ob, oc, od;
        cnt += spike4(a, oa);
        cnt += spike4(b, ob);
        cnt += spike4(c, oc);
        cnt += spike4(d, od);
        out_spikes4[i]             = oa;
        out_spikes4[i +     BLOCK] = ob;
        out_spikes4[i + 2 * BLOCK] = oc;
        out_spikes4[i + 3 * BLOCK] = od;
    }
    for (; i < end; i += BLOCK) {
        v4f s = spikes4[i];
        v4f o;
        cnt += spike4(s, o);
        out_spikes4[i] = o;
    }

    // Block reduction: wave-64 shuffle -> LDS -> thread 0 stores partial.
    #pragma unroll
    for (int off = 32; off > 0; off >>= 1)
        cnt += __shfl_down(cnt, off, 64);

    __shared__ int wave_sums[BLOCK / 64];
    const int lane = tid & 63;
    const int wid  = tid >> 6;
    if (lane == 0) wave_sums[wid] = cnt;
    __syncthreads();
    if (tid == 0) {
        int total = 0;
        #pragma unroll
        for (int w = 0; w < BLOCK / 64; ++w) total += wave_sums[w];
        partials[blockIdx.x] = (unsigned int)total;
    }
}

// Kernel 2: each block redundantly reduces the partials (8 KB, L2-hot),
// then streams delta = S - P over its contiguous chunk.
__global__ __launch_bounds__(BLOCK) void delta_kernel(
    const v4f* __restrict__ P4,
    v4f* __restrict__ delta4,
    const unsigned int* __restrict__ partials,
    int n_part, int n4, int chunk, float inv_n)
{
    const int tid = threadIdx.x;

    int c = 0;
    for (int j = tid; j < n_part; j += BLOCK)
        c += (int)partials[j];
    #pragma unroll
    for (int off = 32; off > 0; off >>= 1)
        c += __shfl_down(c, off, 64);

    __shared__ int wave_sums[BLOCK / 64];
    const int lane = tid & 63;
    const int wid  = tid >> 6;
    if (lane == 0) wave_sums[wid] = c;
    __syncthreads();
    int total = 0;
    #pragma unroll
    for (int w = 0; w < BLOCK / 64; ++w) total += wave_sums[w];
    const float S = (float)total * inv_n;   // exact: total <= 2^25, inv_n = 2^-25

    const int start = blockIdx.x * chunk;
    const int end   = min(start + chunk, n4);
    int i = start + tid;
    for (; i + 3 * BLOCK < end; i += 4 * BLOCK) {
        v4f a  = P4[i];
        v4f b  = P4[i +     BLOCK];
        v4f c4 = P4[i + 2 * BLOCK];
        v4f d  = P4[i + 3 * BLOCK];
        delta4[i]             = S - a;
        delta4[i +     BLOCK] = S - b;
        delta4[i + 2 * BLOCK] = S - c4;
        delta4[i + 3 * BLOCK] = S - d;
    }
    for (; i < end; i += BLOCK) {
        v4f p = P4[i];
        delta4[i] = S - p;
    }
}

extern "C" void kernel_launch(void* const* d_in, const int* in_sizes, int n_in,
                              void* d_out, int out_size, void* d_ws, size_t ws_size,
                              hipStream_t stream) {
    const float* spikes = (const float*)d_in[0];
    const float* P      = (const float*)d_in[1];
    float* out          = (float*)d_out;

    const int n  = in_sizes[0];          // 33554432, divisible by 4
    const int n4 = n / 4;                // 8388608
    const int chunk = (n4 + GRID - 1) / GRID;  // 4096 float4 = 64 KiB per block
    float* delta_out  = out;             // first N floats
    float* spikes_out = out + n;         // second N floats

    unsigned int* partials = (unsigned int*)d_ws;  // GRID u32 slots, fully
                                                   // rewritten each call

    spike_count_kernel<<<GRID, BLOCK, 0, stream>>>(
        (const v4f*)spikes, (v4f*)spikes_out, partials, n4, chunk);

    delta_kernel<<<GRID, BLOCK, 0, stream>>>(
        (const v4f*)P, (v4f*)delta_out, partials, GRID, n4, chunk,
        1.0f / (float)n);
}